// Round 9
// baseline (165.110 us; speedup 1.0000x reference)
//
#include <hip/hip_runtime.h>

typedef short bf16x8 __attribute__((ext_vector_type(8)));
typedef float f32x4 __attribute__((ext_vector_type(4)));

namespace {
constexpr int Bb = 8, Cc = 512, Nn = 16384, Qq = 128;
constexpr float EPS = 1e-5f, SLOPE = 0.01f;
// ws layout (bytes)
constexpr size_t XBF_OFF = 0;                         // B*C*N bf16 = 128 MiB
constexpr size_t QBF_OFF = 134217728;                 // B*Q*N bf16 = 32 MiB (g!=0 path only)
constexpr size_t PART_OFF = QBF_OFF + 33554432;       // B*16*Q*C f32 = 32 MiB
constexpr size_t ATT_OFF = PART_OFF + 33554432;       // B*Q*C bf16 = 1 MiB
constexpr size_t WQA_OFF = ATT_OFF + 1048576;         // Q*C bf16 fragment-major = 128 KiB
constexpr size_t WS_NEED = WQA_OFF + 131072;
constexpr int SPLITK = 16, NSL = Nn / SPLITK;         // 1024
}

__device__ __forceinline__ unsigned short f2bf(float x) {
  unsigned u = __builtin_bit_cast(unsigned, x);
  u += 0x7fffu + ((u >> 16) & 1u);
  return (unsigned short)(u >> 16);
}
__device__ __forceinline__ float bf2f(unsigned short h) {
  return __builtin_bit_cast(float, (unsigned)h << 16);
}
__device__ __forceinline__ int swz(int row, int kc) { return kc ^ ((row >> 1) & 3); }

// read a 16x32 MFMA fragment from an LDS tile with 32 shorts/row (swizzled)
__device__ __forceinline__ bf16x8 ldsfrag(const short* buf, int rowbase, int lane) {
  const int r = rowbase + (lane & 15);
  const int kg = lane >> 4;
  return *(const bf16x8*)&buf[r * 32 + swz(r, kg) * 8];
}
#define MFMA16 __builtin_amdgcn_mfma_f32_16x16x32_bf16

// ============== K0: Wq -> bf16 fragment-major (A-frag = 1KB coalesced) ======
// wqA entry g = (t*8 + r16)*64 + lane  holds Wq[r16*16+(lane&15)]
//                                           [t*32+(lane>>4)*8 .. +7] as bf16x8.
// grid 32 x 256 threads, one 16B entry per thread.
__global__ __launch_bounds__(256) void k0_wqA(
    const float* __restrict__ Wq, unsigned short* __restrict__ wqA)
{
  const int g = blockIdx.x * 256 + threadIdx.x;     // 0..8191
  const int t = g >> 9;
  const int rem = g & 511;
  const int r16 = rem >> 6, lane = rem & 63;
  const int q = r16 * 16 + (lane & 15);
  const int c = t * 32 + (lane >> 4) * 8;
  const float4* s4 = (const float4*)(Wq + q * Cc + c);
  float4 v0 = s4[0], v1 = s4[1];
  bf16x8 pk;
  pk[0] = (short)f2bf(v0.x); pk[1] = (short)f2bf(v0.y);
  pk[2] = (short)f2bf(v0.z); pk[3] = (short)f2bf(v0.w);
  pk[4] = (short)f2bf(v1.x); pk[5] = (short)f2bf(v1.y);
  pk[6] = (short)f2bf(v1.z); pk[7] = (short)f2bf(v1.w);
  *(bf16x8*)&wqA[(size_t)g * 8] = pk;
}

// ============== K1: q = leakyrelu(BN(Wq@x)) -> out (fp32; = answer if g==0)
// R5 distance-1 schedule; A-fragments as coalesced L2 loads (no Ws LDS).
// grid (Nn/128, B), block 256 (4 waves, 2x2 quadrants of 128q x 128n tile)
__global__ __launch_bounds__(256) void k1_qproj(
    const float* __restrict__ x, const unsigned short* __restrict__ wqA,
    const float* __restrict__ bns, const float* __restrict__ bnb,
    const float* __restrict__ bnm, const float* __restrict__ bnv,
    const float* __restrict__ gamma,
    unsigned short* __restrict__ xbf, unsigned short* __restrict__ qbf,
    float* __restrict__ out)
{
  const bool wr = (gamma[0] != 0.f);             // uniform branch
  const int n0 = blockIdx.x * 128;
  const int b  = blockIdx.y;
  const int tid = threadIdx.x;
  const int lane = tid & 63, w = tid >> 6;
  const int wq = (w >> 1) * 64, wn = (w & 1) * 64;
  __shared__ __align__(16) short Xs[2][128 * 32];   // [n][c-chunk32] swizzled (transposed)
  f32x4 acc[4][4] = {};
  const int n2 = tid & 63, cg = tid >> 6;        // Xs staging: 8 channels x 2 n
  // A-fragment pointer: wA[t*512 + fi*64] = 16B, lane-consecutive -> coalesced
  const bf16x8* wA = (const bf16x8*)wqA + (w >> 1) * 256 + lane;

  float2 xv[8];          // prefetched x fp32 (8 channels x 2 n)
  bf16x8 aCur[4], aNxt[4];

  // prologue: A-frags chunk 0 + x chunk 0 stage
  {
    #pragma unroll
    for (int fi = 0; fi < 4; ++fi) aCur[fi] = wA[fi * 64];
    const size_t base = ((size_t)b * Cc + cg * 8) * (size_t)Nn + n0 + n2 * 2;
    #pragma unroll
    for (int k = 0; k < 8; ++k) xv[k] = *(const float2*)&x[base + (size_t)k * Nn];
    bf16x8 pkA, pkB;
    #pragma unroll
    for (int k = 0; k < 8; ++k) {
      unsigned short lo = f2bf(xv[k].x), hi = f2bf(xv[k].y);
      pkA[k] = (short)lo; pkB[k] = (short)hi;
      if (wr) *(unsigned*)&xbf[base + (size_t)k * Nn] = (unsigned)lo | ((unsigned)hi << 16);
    }
    const int ra = n2 * 2, rb = ra + 1;
    *(bf16x8*)&Xs[0][ra * 32 + swz(ra, cg) * 8] = pkA;
    *(bf16x8*)&Xs[0][rb * 32 + swz(rb, cg) * 8] = pkB;
  }
  __syncthreads();

  int cur = 0;
  for (int t = 0; t < 16; ++t) {
    const int c0n = (t + 1) * 32;
    if (t < 15) {  // issue next-chunk loads EARLY (hide under MFMA phase)
      #pragma unroll
      for (int fi = 0; fi < 4; ++fi) aNxt[fi] = wA[(t + 1) * 512 + fi * 64];
      const size_t base = ((size_t)b * Cc + c0n + cg * 8) * (size_t)Nn + n0 + n2 * 2;
      #pragma unroll
      for (int k = 0; k < 8; ++k) xv[k] = *(const float2*)&x[base + (size_t)k * Nn];
    }
    // compute current chunk: B-frags from LDS[cur], A-frags from regs
    bf16x8 bF[4];
    #pragma unroll
    for (int fj = 0; fj < 4; ++fj) bF[fj] = ldsfrag(Xs[cur], wn + fj * 16, lane);
    #pragma unroll
    for (int fi = 0; fi < 4; ++fi)
      #pragma unroll
      for (int fj = 0; fj < 4; ++fj)
        acc[fi][fj] = MFMA16(aCur[fi], bF[fj], acc[fi][fj], 0, 0, 0);
    // write next chunk to the other LDS buffer (waits x loads only here)
    if (t < 15) {
      const int nb = cur ^ 1;
      const size_t base = ((size_t)b * Cc + c0n + cg * 8) * (size_t)Nn + n0 + n2 * 2;
      bf16x8 pkA, pkB;
      #pragma unroll
      for (int k = 0; k < 8; ++k) {
        unsigned short lo = f2bf(xv[k].x), hi = f2bf(xv[k].y);
        pkA[k] = (short)lo; pkB[k] = (short)hi;
        if (wr) *(unsigned*)&xbf[base + (size_t)k * Nn] = (unsigned)lo | ((unsigned)hi << 16);
      }
      const int ra = n2 * 2, rb = ra + 1;
      *(bf16x8*)&Xs[nb][ra * 32 + swz(ra, cg) * 8] = pkA;
      *(bf16x8*)&Xs[nb][rb * 32 + swz(rb, cg) * 8] = pkB;
      #pragma unroll
      for (int fi = 0; fi < 4; ++fi) aCur[fi] = aNxt[fi];
      cur = nb;
    }
    __syncthreads();
  }

  const int cl = lane & 15, rg = lane >> 4;
  #pragma unroll
  for (int fi = 0; fi < 4; ++fi)
    #pragma unroll
    for (int r = 0; r < 4; ++r) {
      const int q = wq + fi * 16 + rg * 4 + r;
      const float inv = bns[q] * rsqrtf(bnv[q] + EPS);
      const float mu = bnm[q], bia = bnb[q];
      #pragma unroll
      for (int fj = 0; fj < 4; ++fj) {
        float t = (acc[fi][fj][r] - mu) * inv + bia;
        t = t >= 0.f ? t : SLOPE * t;
        const size_t idx = ((size_t)b * Qq + q) * Nn + n0 + wn + fj * 16 + cl;
        out[idx] = t;                       // q term; exact answer when g==0
        if (wr) qbf[idx] = f2bf(t);         // attention path input
      }
    }
}

// ============== K2: part[bs][q][c] = sum_{n in slice} q_bf * x_bf ===========
// grid (B*SPLITK=128, Cc/128=4), block 256. No-op when gamma == 0.
__global__ __launch_bounds__(256) void k2_energy(
    const unsigned short* __restrict__ xbf, const unsigned short* __restrict__ qbf,
    const float* __restrict__ gamma, float* __restrict__ part)
{
  if (gamma[0] == 0.f) return;
  const int bs = blockIdx.x;
  const int b = bs >> 4, s = bs & 15;
  const int c0 = blockIdx.y * 128;
  const int ns = s * NSL;
  const int tid = threadIdx.x;
  const int lane = tid & 63, w = tid >> 6;
  const int wq = (w >> 1) * 64, wc = (w & 1) * 64;
  __shared__ __align__(16) short Qs[128 * 32];   // [q][n-chunk32]
  __shared__ __align__(16) short Xs[128 * 32];   // [c][n-chunk32]
  f32x4 acc[4][4] = {};
  const int row = tid >> 1, kc2 = (tid & 1) * 2;
  const unsigned short* qrow_p = qbf + ((size_t)b * Qq + row) * Nn + ns;
  const unsigned short* xrow_p = xbf + ((size_t)b * Cc + c0 + row) * Nn + ns;

  for (int nb = 0; nb < NSL; nb += 32) {
    #pragma unroll
    for (int eh = 0; eh < 2; ++eh) {
      const int kc = kc2 + eh;
      uint4 vq = *(const uint4*)&qrow_p[nb + kc * 8];
      *(uint4*)&Qs[row * 32 + swz(row, kc) * 8] = vq;
      uint4 vx = *(const uint4*)&xrow_p[nb + kc * 8];
      *(uint4*)&Xs[row * 32 + swz(row, kc) * 8] = vx;
    }
    __syncthreads();
    bf16x8 aF[4], bF[4];
    #pragma unroll
    for (int fi = 0; fi < 4; ++fi) aF[fi] = ldsfrag(Qs, wq + fi * 16, lane);
    #pragma unroll
    for (int fj = 0; fj < 4; ++fj) bF[fj] = ldsfrag(Xs, wc + fj * 16, lane);
    #pragma unroll
    for (int fi = 0; fi < 4; ++fi)
      #pragma unroll
      for (int fj = 0; fj < 4; ++fj)
        acc[fi][fj] = MFMA16(aF[fi], bF[fj], acc[fi][fj], 0, 0, 0);
    __syncthreads();
  }
  const int cl = lane & 15, rg = lane >> 4;
  #pragma unroll
  for (int fi = 0; fi < 4; ++fi)
    #pragma unroll
    for (int fj = 0; fj < 4; ++fj)
      #pragma unroll
      for (int r = 0; r < 4; ++r) {
        const int q = wq + fi * 16 + rg * 4 + r;
        const int c = c0 + wc + fj * 16 + cl;
        part[((size_t)bs * Qq + q) * Cc + c] = acc[fi][fj][r];
      }
}

// ============== K3: att_bf = softmax(max-e) = exp(min_e - e)/Z ==============
// grid (B*Q/4), block 256: one wave per (b,q) row. No-op when gamma == 0.
__global__ __launch_bounds__(256) void k3_softmax(
    const float* __restrict__ part, const float* __restrict__ gamma,
    unsigned short* __restrict__ attbf)
{
  if (gamma[0] == 0.f) return;
  const int row = blockIdx.x * 4 + (threadIdx.x >> 6);   // b*Qq + q
  const int b = row >> 7, q = row & 127;
  const int lane = threadIdx.x & 63;
  float e[8] = {};
  for (int s = 0; s < SPLITK; ++s) {
    const float4* p = (const float4*)&part[((size_t)(b * SPLITK + s) * Qq + q) * Cc + lane * 8];
    float4 v0 = p[0], v1 = p[1];
    e[0] += v0.x; e[1] += v0.y; e[2] += v0.z; e[3] += v0.w;
    e[4] += v1.x; e[5] += v1.y; e[6] += v1.z; e[7] += v1.w;
  }
  float mn = e[0];
  #pragma unroll
  for (int j = 1; j < 8; ++j) mn = fminf(mn, e[j]);
  #pragma unroll
  for (int m = 1; m < 64; m <<= 1) mn = fminf(mn, __shfl_xor(mn, m));
  float wgt[8], z = 0.f;
  #pragma unroll
  for (int j = 0; j < 8; ++j) { wgt[j] = __expf(mn - e[j]); z += wgt[j]; }
  #pragma unroll
  for (int m = 1; m < 64; m <<= 1) z += __shfl_xor(z, m);
  const float rz = 1.f / z;
  bf16x8 pk;
  #pragma unroll
  for (int j = 0; j < 8; ++j) pk[j] = (short)f2bf(wgt[j] * rz);
  *(bf16x8*)&attbf[(size_t)row * Cc + lane * 8] = pk;
}

// ============== K4: out += gamma*(att@x)  (q term already in out) ===========
// grid (Nn/128, B), block 256. No-op when gamma == 0.
__global__ __launch_bounds__(256) void k4_out(
    const unsigned short* __restrict__ xbf, const unsigned short* __restrict__ attbf,
    const float* __restrict__ gamma, float* __restrict__ out)
{
  const float g = gamma[0];
  if (g == 0.f) return;
  const int n0 = blockIdx.x * 128;
  const int b  = blockIdx.y;
  const int tid = threadIdx.x;
  const int lane = tid & 63, w = tid >> 6;
  const int wq = (w >> 1) * 64, wn = (w & 1) * 64;
  __shared__ __align__(16) short As[128 * 32];   // [q][c-chunk32]
  __shared__ __align__(16) short Xs[128 * 32];   // [n][c-chunk32] transposed
  f32x4 acc[4][4] = {};
  const int tq = tid >> 1, th = tid & 1;         // As staging
  const int n2 = tid & 63, cg = tid >> 6;        // Xs staging

  for (int c0 = 0; c0 < Cc; c0 += 32) {
    #pragma unroll
    for (int eh = 0; eh < 2; ++eh) {
      const int kc = th * 2 + eh;
      uint4 v = *(const uint4*)&attbf[((size_t)b * Qq + tq) * Cc + c0 + kc * 8];
      *(uint4*)&As[tq * 32 + swz(tq, kc) * 8] = v;
    }
    {
      const size_t base = ((size_t)b * Cc + c0 + cg * 8) * (size_t)Nn + n0 + n2 * 2;
      bf16x8 pkA, pkB;
      #pragma unroll
      for (int k = 0; k < 8; ++k) {
        unsigned d = *(const unsigned*)&xbf[base + (size_t)k * Nn];
        pkA[k] = (short)(d & 0xffffu);
        pkB[k] = (short)(d >> 16);
      }
      const int ra = n2 * 2, rb = ra + 1;
      *(bf16x8*)&Xs[ra * 32 + swz(ra, cg) * 8] = pkA;
      *(bf16x8*)&Xs[rb * 32 + swz(rb, cg) * 8] = pkB;
    }
    __syncthreads();
    bf16x8 aF[4], bF[4];
    #pragma unroll
    for (int fi = 0; fi < 4; ++fi) aF[fi] = ldsfrag(As, wq + fi * 16, lane);
    #pragma unroll
    for (int fj = 0; fj < 4; ++fj) bF[fj] = ldsfrag(Xs, wn + fj * 16, lane);
    #pragma unroll
    for (int fi = 0; fi < 4; ++fi)
      #pragma unroll
      for (int fj = 0; fj < 4; ++fj)
        acc[fi][fj] = MFMA16(aF[fi], bF[fj], acc[fi][fj], 0, 0, 0);
    __syncthreads();
  }
  const int cl = lane & 15, rg = lane >> 4;
  #pragma unroll
  for (int fi = 0; fi < 4; ++fi)
    #pragma unroll
    for (int r = 0; r < 4; ++r) {
      const int q = wq + fi * 16 + rg * 4 + r;
      #pragma unroll
      for (int fj = 0; fj < 4; ++fj) {
        const size_t idx = ((size_t)b * Qq + q) * Nn + n0 + wn + fj * 16 + cl;
        out[idx] = g * acc[fi][fj][r] + out[idx];
      }
    }
}

// ======================= fallback fp32 path (round-1) =======================
namespace old {
constexpr int SPLIT = 4, NS = Nn / SPLIT;

__global__ __launch_bounds__(256) void k_qproj(
    const float* __restrict__ x, const float* __restrict__ Wq,
    const float* __restrict__ bns, const float* __restrict__ bnb,
    const float* __restrict__ bnm, const float* __restrict__ bnv,
    float* __restrict__ qout)
{
  const int n0 = blockIdx.x * 64;
  const int b  = blockIdx.y;
  const int tid = threadIdx.x;
  const int tn = tid & 15, tq = tid >> 4;
  __shared__ float wS[128][33];
  __shared__ float xS[32][64];
  float acc[8][4] = {};
  const float* xb = x + (size_t)b * Cc * Nn;
  for (int c0 = 0; c0 < Cc; c0 += 32) {
    for (int k = tid; k < 128 * 32; k += 256) {
      int r = k >> 5, cc = k & 31;
      wS[r][cc] = Wq[r * Cc + c0 + cc];
    }
    for (int k = tid; k < 32 * 64; k += 256) {
      int cc = k >> 6, nn = k & 63;
      xS[cc][nn] = xb[(size_t)(c0 + cc) * Nn + n0 + nn];
    }
    __syncthreads();
    #pragma unroll 8
    for (int cc = 0; cc < 32; ++cc) {
      float av[8], bv[4];
      #pragma unroll
      for (int i = 0; i < 8; ++i) av[i] = wS[tq * 8 + i][cc];
      #pragma unroll
      for (int j = 0; j < 4; ++j) bv[j] = xS[cc][tn * 4 + j];
      #pragma unroll
      for (int i = 0; i < 8; ++i)
        #pragma unroll
        for (int j = 0; j < 4; ++j)
          acc[i][j] += av[i] * bv[j];
    }
    __syncthreads();
  }
  #pragma unroll
  for (int i = 0; i < 8; ++i) {
    const int q = tq * 8 + i;
    const float inv = bns[q] * rsqrtf(bnv[q] + EPS);
    const float mu = bnm[q], bia = bnb[q];
    float4 v;
    float* vp = &v.x;
    #pragma unroll
    for (int j = 0; j < 4; ++j) {
      float t = (acc[i][j] - mu) * inv + bia;
      vp[j] = t >= 0.f ? t : SLOPE * t;
    }
    *(float4*)&qout[((size_t)b * Qq + q) * Nn + n0 + tn * 4] = v;
  }
}

__global__ __launch_bounds__(256) void k_energy(
    const float* __restrict__ x, const float* __restrict__ qf,
    float* __restrict__ part)
{
  const int q0 = blockIdx.x * 64;
  const int c0 = blockIdx.y * 64;
  const int b  = blockIdx.z / SPLIT;
  const int s  = blockIdx.z % SPLIT;
  const int tid = threadIdx.x;
  const int tc = tid & 15, tq = tid >> 4;
  __shared__ float qS[32][69];
  __shared__ float xS[32][69];
  float acc[4][4] = {};
  const float* xb = x  + ((size_t)b * Cc + c0) * Nn + s * NS;
  const float* qb = qf + ((size_t)b * Qq + q0) * Nn + s * NS;
  for (int nb = 0; nb < NS; nb += 32) {
    for (int k = tid; k < 64 * 32; k += 256) {
      int r = k >> 5, nn = k & 31;
      qS[nn][r] = qb[(size_t)r * Nn + nb + nn];
      xS[nn][r] = xb[(size_t)r * Nn + nb + nn];
    }
    __syncthreads();
    #pragma unroll 8
    for (int nn = 0; nn < 32; ++nn) {
      float av[4], bv[4];
      #pragma unroll
      for (int i = 0; i < 4; ++i) av[i] = qS[nn][tq * 4 + i];
      #pragma unroll
      for (int j = 0; j < 4; ++j) bv[j] = xS[nn][tc * 4 + j];
      #pragma unroll
      for (int i = 0; i < 4; ++i)
        #pragma unroll
        for (int j = 0; j < 4; ++j)
          acc[i][j] += av[i] * bv[j];
    }
    __syncthreads();
  }
  float* pb = part + (size_t)(b * SPLIT + s) * Qq * Cc;
  #pragma unroll
  for (int i = 0; i < 4; ++i) {
    float4 v = make_float4(acc[i][0], acc[i][1], acc[i][2], acc[i][3]);
    *(float4*)&pb[(size_t)(q0 + tq * 4 + i) * Cc + c0 + tc * 4] = v;
  }
}

__global__ __launch_bounds__(64) void k_softmax(
    const float* __restrict__ part, float* __restrict__ att)
{
  const int row = blockIdx.x;
  const int b = row >> 7, q = row & 127;
  const int lane = threadIdx.x;
  float e[8];
  #pragma unroll
  for (int j = 0; j < 8; ++j) {
    const int c = lane + 64 * j;
    float v = 0.f;
    #pragma unroll
    for (int s = 0; s < SPLIT; ++s)
      v += part[((size_t)(b * SPLIT + s) * Qq + q) * Cc + c];
    e[j] = v;
  }
  float mn = e[0];
  #pragma unroll
  for (int j = 1; j < 8; ++j) mn = fminf(mn, e[j]);
  #pragma unroll
  for (int m = 1; m < 64; m <<= 1) mn = fminf(mn, __shfl_xor(mn, m));
  float wv[8], z = 0.f;
  #pragma unroll
  for (int j = 0; j < 8; ++j) { wv[j] = expf(mn - e[j]); z += wv[j]; }
  #pragma unroll
  for (int m = 1; m < 64; m <<= 1) z += __shfl_xor(z, m);
  const float rz = 1.f / z;
  #pragma unroll
  for (int j = 0; j < 8; ++j)
    att[(size_t)row * Cc + lane + 64 * j] = wv[j] * rz;
}

__global__ __launch_bounds__(256) void k_out(
    const float* __restrict__ x, const float* __restrict__ att,
    const float* __restrict__ gamma, float* __restrict__ out)
{
  const int n0 = blockIdx.x * 64;
  const int b  = blockIdx.y;
  const int tid = threadIdx.x;
  const int tn = tid & 15, tq = tid >> 4;
  __shared__ float aS[128][33];
  __shared__ float xS[32][64];
  float acc[8][4] = {};
  const float* xb = x + (size_t)b * Cc * Nn;
  const float* ab = att + (size_t)b * Qq * Cc;
  for (int c0 = 0; c0 < Cc; c0 += 32) {
    for (int k = tid; k < 128 * 32; k += 256) {
      int r = k >> 5, cc = k & 31;
      aS[r][cc] = ab[r * Cc + c0 + cc];
    }
    for (int k = tid; k < 32 * 64; k += 256) {
      int cc = k >> 6, nn = k & 63;
      xS[cc][nn] = xb[(size_t)(c0 + cc) * Nn + n0 + nn];
    }
    __syncthreads();
    #pragma unroll 8
    for (int cc = 0; cc < 32; ++cc) {
      float av[8], bv[4];
      #pragma unroll
      for (int i = 0; i < 8; ++i) av[i] = aS[tq * 8 + i][cc];
      #pragma unroll
      for (int j = 0; j < 4; ++j) bv[j] = xS[cc][tn * 4 + j];
      #pragma unroll
      for (int i = 0; i < 8; ++i)
        #pragma unroll
        for (int j = 0; j < 4; ++j)
          acc[i][j] += av[i] * bv[j];
    }
    __syncthreads();
  }
  const float g = gamma[0];
  #pragma unroll
  for (int i = 0; i < 8; ++i) {
    const int q = tq * 8 + i;
    const size_t idx = ((size_t)b * Qq + q) * Nn + n0 + tn * 4;
    float4 qv = *(const float4*)&out[idx];
    float4 v;
    v.x = g * acc[i][0] + qv.x;
    v.y = g * acc[i][1] + qv.y;
    v.z = g * acc[i][2] + qv.z;
    v.w = g * acc[i][3] + qv.w;
    *(float4*)&out[idx] = v;
  }
}
} // namespace old

extern "C" void kernel_launch(void* const* d_in, const int* in_sizes, int n_in,
                              void* d_out, int out_size, void* d_ws, size_t ws_size,
                              hipStream_t stream) {
  (void)in_sizes; (void)n_in; (void)out_size;
  const float* x   = (const float*)d_in[0];
  const float* Wq  = (const float*)d_in[1];
  const float* bns = (const float*)d_in[2];
  const float* bnb = (const float*)d_in[3];
  const float* bnm = (const float*)d_in[4];
  const float* bnv = (const float*)d_in[5];
  const float* gam = (const float*)d_in[6];
  float* out = (float*)d_out;

  if (ws_size >= WS_NEED) {
    unsigned short* xbf  = (unsigned short*)((char*)d_ws + XBF_OFF);
    unsigned short* qbf  = (unsigned short*)((char*)d_ws + QBF_OFF);
    float*          part = (float*)((char*)d_ws + PART_OFF);
    unsigned short* attb = (unsigned short*)((char*)d_ws + ATT_OFF);
    unsigned short* wqA  = (unsigned short*)((char*)d_ws + WQA_OFF);

    k0_wqA<<<dim3(32), 256, 0, stream>>>(Wq, wqA);
    k1_qproj<<<dim3(Nn / 128, Bb), 256, 0, stream>>>(x, wqA, bns, bnb, bnm, bnv, gam, xbf, qbf, out);
    k2_energy<<<dim3(Bb * SPLITK, Cc / 128), 256, 0, stream>>>(xbf, qbf, gam, part);
    k3_softmax<<<dim3(Bb * Qq / 4), 256, 0, stream>>>(part, gam, attb);
    k4_out<<<dim3(Nn / 128, Bb), 256, 0, stream>>>(xbf, attb, gam, out);
  } else {
    float* part = (float*)d_ws;
    float* att  = part + (size_t)Bb * old::SPLIT * Qq * Cc;
    old::k_qproj<<<dim3(Nn / 64, Bb), 256, 0, stream>>>(x, Wq, bns, bnb, bnm, bnv, out);
    old::k_energy<<<dim3(Qq / 64, Cc / 64, Bb * old::SPLIT), 256, 0, stream>>>(x, out, part);
    old::k_softmax<<<dim3(Bb * Qq), 64, 0, stream>>>(part, att);
    old::k_out<<<dim3(Nn / 64, Bb), 256, 0, stream>>>(x, att, gam, out);
  }
}

// Round 10
// 91.266 us; speedup vs baseline: 1.8091x; 1.8091x over previous
//
#include <hip/hip_runtime.h>

typedef short bf16x8 __attribute__((ext_vector_type(8)));
typedef float f32x4 __attribute__((ext_vector_type(4)));

namespace {
constexpr int Bb = 8, Cc = 512, Nn = 16384, Qq = 128;
constexpr float EPS = 1e-5f, SLOPE = 0.01f;
// ws layout (bytes)
constexpr size_t XBF_OFF = 0;                         // B*C*N bf16 = 128 MiB
constexpr size_t QBF_OFF = 134217728;                 // B*Q*N bf16 = 32 MiB (g!=0 path only)
constexpr size_t PART_OFF = QBF_OFF + 33554432;       // B*16*Q*C f32 = 32 MiB
constexpr size_t ATT_OFF = PART_OFF + 33554432;       // B*Q*C bf16 = 1 MiB
constexpr size_t WQBF_OFF = ATT_OFF + 1048576;        // Q*C bf16 = 128 KiB
constexpr size_t WS_NEED = WQBF_OFF + 131072;
constexpr int SPLITK = 16, NSL = Nn / SPLITK;         // 1024
}

__device__ __forceinline__ unsigned short f2bf(float x) {
  unsigned u = __builtin_bit_cast(unsigned, x);
  u += 0x7fffu + ((u >> 16) & 1u);
  return (unsigned short)(u >> 16);
}
__device__ __forceinline__ float bf2f(unsigned short h) {
  return __builtin_bit_cast(float, (unsigned)h << 16);
}
__device__ __forceinline__ int swz(int row, int kc) { return kc ^ ((row >> 1) & 3); }

// read a 16x32 MFMA fragment from an LDS tile with 32 shorts/row (swizzled)
__device__ __forceinline__ bf16x8 ldsfrag(const short* buf, int rowbase, int lane) {
  const int r = rowbase + (lane & 15);
  const int kg = lane >> 4;
  return *(const bf16x8*)&buf[r * 32 + swz(r, kg) * 8];
}
#define MFMA16 __builtin_amdgcn_mfma_f32_16x16x32_bf16

// ============== K0: Wq -> bf16 (once; L2-resident thereafter) ==============
__global__ __launch_bounds__(256) void k0_wqbf(
    const float* __restrict__ Wq, unsigned short* __restrict__ wqbf)
{
  const int i = (blockIdx.x * 256 + threadIdx.x) * 4;
  float4 v = *(const float4*)&Wq[i];
  uint2 o;
  o.x = (unsigned)f2bf(v.x) | ((unsigned)f2bf(v.y) << 16);
  o.y = (unsigned)f2bf(v.z) | ((unsigned)f2bf(v.w) << 16);
  *(uint2*)&wqbf[i] = o;
}

// ============== K1: q = leakyrelu(BN(Wq@x)) -> out (fp32; = answer if g==0)
// 2-phase pipelined: prefetch chunk t+1 to regs || MFMA chunk t; dbuf LDS.
// grid (Nn/128, B), block 256 (4 waves, 2x2 quadrants of 128q x 128n tile)
__global__ __launch_bounds__(256) void k1_qproj(
    const float* __restrict__ x, const unsigned short* __restrict__ wqbf,
    const float* __restrict__ bns, const float* __restrict__ bnb,
    const float* __restrict__ bnm, const float* __restrict__ bnv,
    const float* __restrict__ gamma,
    unsigned short* __restrict__ xbf, unsigned short* __restrict__ qbf,
    float* __restrict__ out)
{
  const bool wr = (gamma[0] != 0.f);             // uniform branch
  const int n0 = blockIdx.x * 128;
  const int b  = blockIdx.y;
  const int tid = threadIdx.x;
  const int lane = tid & 63, w = tid >> 6;
  const int wq = (w >> 1) * 64, wn = (w & 1) * 64;
  __shared__ __align__(16) short Ws[2][128 * 32];   // [q][c-chunk32] swizzled
  __shared__ __align__(16) short Xs[2][128 * 32];   // [n][c-chunk32] swizzled (transposed)
  f32x4 acc[4][4] = {};
  const int tq = tid >> 1, th = tid & 1;         // Ws staging: row tq, c-half th
  const int n2 = tid & 63, cg = tid >> 6;        // Xs staging: 8 channels x 2 n

  uint4  wv0, wv1;    // prefetched Wq bf16 (2 x 8 elems)
  float2 xv[8];       // prefetched x fp32 (8 channels x 2 n)

  // prologue: load + store chunk 0
  {
    wv0 = *(const uint4*)&wqbf[tq * Cc + 0 + (th * 2 + 0) * 8];
    wv1 = *(const uint4*)&wqbf[tq * Cc + 0 + (th * 2 + 1) * 8];
    const size_t base = ((size_t)b * Cc + 0 + cg * 8) * (size_t)Nn + n0 + n2 * 2;
    #pragma unroll
    for (int k = 0; k < 8; ++k) xv[k] = *(const float2*)&x[base + (size_t)k * Nn];
    *(uint4*)&Ws[0][tq * 32 + swz(tq, th * 2 + 0) * 8] = wv0;
    *(uint4*)&Ws[0][tq * 32 + swz(tq, th * 2 + 1) * 8] = wv1;
    bf16x8 pkA, pkB;
    #pragma unroll
    for (int k = 0; k < 8; ++k) {
      unsigned short lo = f2bf(xv[k].x), hi = f2bf(xv[k].y);
      pkA[k] = (short)lo; pkB[k] = (short)hi;
      if (wr) *(unsigned*)&xbf[base + (size_t)k * Nn] = (unsigned)lo | ((unsigned)hi << 16);
    }
    const int ra = n2 * 2, rb = ra + 1;
    *(bf16x8*)&Xs[0][ra * 32 + swz(ra, cg) * 8] = pkA;
    *(bf16x8*)&Xs[0][rb * 32 + swz(rb, cg) * 8] = pkB;
  }
  __syncthreads();

  int cur = 0;
  for (int t = 0; t < 16; ++t) {
    const int c0n = (t + 1) * 32;
    if (t < 15) {  // issue next-chunk global loads EARLY (latency hides under MFMA)
      wv0 = *(const uint4*)&wqbf[tq * Cc + c0n + (th * 2 + 0) * 8];
      wv1 = *(const uint4*)&wqbf[tq * Cc + c0n + (th * 2 + 1) * 8];
      const size_t base = ((size_t)b * Cc + c0n + cg * 8) * (size_t)Nn + n0 + n2 * 2;
      #pragma unroll
      for (int k = 0; k < 8; ++k) xv[k] = *(const float2*)&x[base + (size_t)k * Nn];
    }
    // compute current chunk from LDS[cur]
    bf16x8 aF[4], bF[4];
    #pragma unroll
    for (int fi = 0; fi < 4; ++fi) aF[fi] = ldsfrag(Ws[cur], wq + fi * 16, lane);
    #pragma unroll
    for (int fj = 0; fj < 4; ++fj) bF[fj] = ldsfrag(Xs[cur], wn + fj * 16, lane);
    #pragma unroll
    for (int fi = 0; fi < 4; ++fi)
      #pragma unroll
      for (int fj = 0; fj < 4; ++fj)
        acc[fi][fj] = MFMA16(aF[fi], bF[fj], acc[fi][fj], 0, 0, 0);
    // write next chunk to the other buffer (waits loads only here)
    if (t < 15) {
      const int nb = cur ^ 1;
      *(uint4*)&Ws[nb][tq * 32 + swz(tq, th * 2 + 0) * 8] = wv0;
      *(uint4*)&Ws[nb][tq * 32 + swz(tq, th * 2 + 1) * 8] = wv1;
      const size_t base = ((size_t)b * Cc + c0n + cg * 8) * (size_t)Nn + n0 + n2 * 2;
      bf16x8 pkA, pkB;
      #pragma unroll
      for (int k = 0; k < 8; ++k) {
        unsigned short lo = f2bf(xv[k].x), hi = f2bf(xv[k].y);
        pkA[k] = (short)lo; pkB[k] = (short)hi;
        if (wr) *(unsigned*)&xbf[base + (size_t)k * Nn] = (unsigned)lo | ((unsigned)hi << 16);
      }
      const int ra = n2 * 2, rb = ra + 1;
      *(bf16x8*)&Xs[nb][ra * 32 + swz(ra, cg) * 8] = pkA;
      *(bf16x8*)&Xs[nb][rb * 32 + swz(rb, cg) * 8] = pkB;
      cur = nb;
    }
    __syncthreads();
  }

  const int cl = lane & 15, rg = lane >> 4;
  #pragma unroll
  for (int fi = 0; fi < 4; ++fi)
    #pragma unroll
    for (int r = 0; r < 4; ++r) {
      const int q = wq + fi * 16 + rg * 4 + r;
      const float inv = bns[q] * rsqrtf(bnv[q] + EPS);
      const float mu = bnm[q], bia = bnb[q];
      #pragma unroll
      for (int fj = 0; fj < 4; ++fj) {
        float t = (acc[fi][fj][r] - mu) * inv + bia;
        t = t >= 0.f ? t : SLOPE * t;
        const size_t idx = ((size_t)b * Qq + q) * Nn + n0 + wn + fj * 16 + cl;
        out[idx] = t;                       // q term; exact answer when g==0
        if (wr) qbf[idx] = f2bf(t);         // attention path input
      }
    }
}

// ============== K2: part[bs][q][c] = sum_{n in slice} q_bf * x_bf ===========
// grid (B*SPLITK=128, Cc/128=4), block 256. No-op when gamma == 0.
__global__ __launch_bounds__(256) void k2_energy(
    const unsigned short* __restrict__ xbf, const unsigned short* __restrict__ qbf,
    const float* __restrict__ gamma, float* __restrict__ part)
{
  if (gamma[0] == 0.f) return;
  const int bs = blockIdx.x;
  const int b = bs >> 4, s = bs & 15;
  const int c0 = blockIdx.y * 128;
  const int ns = s * NSL;
  const int tid = threadIdx.x;
  const int lane = tid & 63, w = tid >> 6;
  const int wq = (w >> 1) * 64, wc = (w & 1) * 64;
  __shared__ __align__(16) short Qs[128 * 32];   // [q][n-chunk32]
  __shared__ __align__(16) short Xs[128 * 32];   // [c][n-chunk32]
  f32x4 acc[4][4] = {};
  const int row = tid >> 1, kc2 = (tid & 1) * 2;
  const unsigned short* qrow_p = qbf + ((size_t)b * Qq + row) * Nn + ns;
  const unsigned short* xrow_p = xbf + ((size_t)b * Cc + c0 + row) * Nn + ns;

  for (int nb = 0; nb < NSL; nb += 32) {
    #pragma unroll
    for (int eh = 0; eh < 2; ++eh) {
      const int kc = kc2 + eh;
      uint4 vq = *(const uint4*)&qrow_p[nb + kc * 8];
      *(uint4*)&Qs[row * 32 + swz(row, kc) * 8] = vq;
      uint4 vx = *(const uint4*)&xrow_p[nb + kc * 8];
      *(uint4*)&Xs[row * 32 + swz(row, kc) * 8] = vx;
    }
    __syncthreads();
    bf16x8 aF[4], bF[4];
    #pragma unroll
    for (int fi = 0; fi < 4; ++fi) aF[fi] = ldsfrag(Qs, wq + fi * 16, lane);
    #pragma unroll
    for (int fj = 0; fj < 4; ++fj) bF[fj] = ldsfrag(Xs, wc + fj * 16, lane);
    #pragma unroll
    for (int fi = 0; fi < 4; ++fi)
      #pragma unroll
      for (int fj = 0; fj < 4; ++fj)
        acc[fi][fj] = MFMA16(aF[fi], bF[fj], acc[fi][fj], 0, 0, 0);
    __syncthreads();
  }
  const int cl = lane & 15, rg = lane >> 4;
  #pragma unroll
  for (int fi = 0; fi < 4; ++fi)
    #pragma unroll
    for (int fj = 0; fj < 4; ++fj)
      #pragma unroll
      for (int r = 0; r < 4; ++r) {
        const int q = wq + fi * 16 + rg * 4 + r;
        const int c = c0 + wc + fj * 16 + cl;
        part[((size_t)bs * Qq + q) * Cc + c] = acc[fi][fj][r];
      }
}

// ============== K3: att_bf = softmax(max-e) = exp(min_e - e)/Z ==============
// grid (B*Q/4), block 256: one wave per (b,q) row. No-op when gamma == 0.
__global__ __launch_bounds__(256) void k3_softmax(
    const float* __restrict__ part, const float* __restrict__ gamma,
    unsigned short* __restrict__ attbf)
{
  if (gamma[0] == 0.f) return;
  const int row = blockIdx.x * 4 + (threadIdx.x >> 6);   // b*Qq + q
  const int b = row >> 7, q = row & 127;
  const int lane = threadIdx.x & 63;
  float e[8] = {};
  for (int s = 0; s < SPLITK; ++s) {
    const float4* p = (const float4*)&part[((size_t)(b * SPLITK + s) * Qq + q) * Cc + lane * 8];
    float4 v0 = p[0], v1 = p[1];
    e[0] += v0.x; e[1] += v0.y; e[2] += v0.z; e[3] += v0.w;
    e[4] += v1.x; e[5] += v1.y; e[6] += v1.z; e[7] += v1.w;
  }
  float mn = e[0];
  #pragma unroll
  for (int j = 1; j < 8; ++j) mn = fminf(mn, e[j]);
  #pragma unroll
  for (int m = 1; m < 64; m <<= 1) mn = fminf(mn, __shfl_xor(mn, m));
  float wgt[8], z = 0.f;
  #pragma unroll
  for (int j = 0; j < 8; ++j) { wgt[j] = __expf(mn - e[j]); z += wgt[j]; }
  #pragma unroll
  for (int m = 1; m < 64; m <<= 1) z += __shfl_xor(z, m);
  const float rz = 1.f / z;
  bf16x8 pk;
  #pragma unroll
  for (int j = 0; j < 8; ++j) pk[j] = (short)f2bf(wgt[j] * rz);
  *(bf16x8*)&attbf[(size_t)row * Cc + lane * 8] = pk;
}

// ============== K4: out += gamma*(att@x)  (q term already in out) ===========
// grid (Nn/128, B), block 256. No-op when gamma == 0.
__global__ __launch_bounds__(256) void k4_out(
    const unsigned short* __restrict__ xbf, const unsigned short* __restrict__ attbf,
    const float* __restrict__ gamma, float* __restrict__ out)
{
  const float g = gamma[0];
  if (g == 0.f) return;
  const int n0 = blockIdx.x * 128;
  const int b  = blockIdx.y;
  const int tid = threadIdx.x;
  const int lane = tid & 63, w = tid >> 6;
  const int wq = (w >> 1) * 64, wn = (w & 1) * 64;
  __shared__ __align__(16) short As[128 * 32];   // [q][c-chunk32]
  __shared__ __align__(16) short Xs[128 * 32];   // [n][c-chunk32] transposed
  f32x4 acc[4][4] = {};
  const int tq = tid >> 1, th = tid & 1;         // As staging
  const int n2 = tid & 63, cg = tid >> 6;        // Xs staging

  for (int c0 = 0; c0 < Cc; c0 += 32) {
    #pragma unroll
    for (int eh = 0; eh < 2; ++eh) {
      const int kc = th * 2 + eh;
      uint4 v = *(const uint4*)&attbf[((size_t)b * Qq + tq) * Cc + c0 + kc * 8];
      *(uint4*)&As[tq * 32 + swz(tq, kc) * 8] = v;
    }
    {
      const size_t base = ((size_t)b * Cc + c0 + cg * 8) * (size_t)Nn + n0 + n2 * 2;
      bf16x8 pkA, pkB;
      #pragma unroll
      for (int k = 0; k < 8; ++k) {
        unsigned d = *(const unsigned*)&xbf[base + (size_t)k * Nn];
        pkA[k] = (short)(d & 0xffffu);
        pkB[k] = (short)(d >> 16);
      }
      const int ra = n2 * 2, rb = ra + 1;
      *(bf16x8*)&Xs[ra * 32 + swz(ra, cg) * 8] = pkA;
      *(bf16x8*)&Xs[rb * 32 + swz(rb, cg) * 8] = pkB;
    }
    __syncthreads();
    bf16x8 aF[4], bF[4];
    #pragma unroll
    for (int fi = 0; fi < 4; ++fi) aF[fi] = ldsfrag(As, wq + fi * 16, lane);
    #pragma unroll
    for (int fj = 0; fj < 4; ++fj) bF[fj] = ldsfrag(Xs, wn + fj * 16, lane);
    #pragma unroll
    for (int fi = 0; fi < 4; ++fi)
      #pragma unroll
      for (int fj = 0; fj < 4; ++fj)
        acc[fi][fj] = MFMA16(aF[fi], bF[fj], acc[fi][fj], 0, 0, 0);
    __syncthreads();
  }
  const int cl = lane & 15, rg = lane >> 4;
  #pragma unroll
  for (int fi = 0; fi < 4; ++fi)
    #pragma unroll
    for (int r = 0; r < 4; ++r) {
      const int q = wq + fi * 16 + rg * 4 + r;
      #pragma unroll
      for (int fj = 0; fj < 4; ++fj) {
        const size_t idx = ((size_t)b * Qq + q) * Nn + n0 + wn + fj * 16 + cl;
        out[idx] = g * acc[fi][fj][r] + out[idx];
      }
    }
}

// ======================= fallback fp32 path (round-1) =======================
namespace old {
constexpr int SPLIT = 4, NS = Nn / SPLIT;

__global__ __launch_bounds__(256) void k_qproj(
    const float* __restrict__ x, const float* __restrict__ Wq,
    const float* __restrict__ bns, const float* __restrict__ bnb,
    const float* __restrict__ bnm, const float* __restrict__ bnv,
    float* __restrict__ qout)
{
  const int n0 = blockIdx.x * 64;
  const int b  = blockIdx.y;
  const int tid = threadIdx.x;
  const int tn = tid & 15, tq = tid >> 4;
  __shared__ float wS[128][33];
  __shared__ float xS[32][64];
  float acc[8][4] = {};
  const float* xb = x + (size_t)b * Cc * Nn;
  for (int c0 = 0; c0 < Cc; c0 += 32) {
    for (int k = tid; k < 128 * 32; k += 256) {
      int r = k >> 5, cc = k & 31;
      wS[r][cc] = Wq[r * Cc + c0 + cc];
    }
    for (int k = tid; k < 32 * 64; k += 256) {
      int cc = k >> 6, nn = k & 63;
      xS[cc][nn] = xb[(size_t)(c0 + cc) * Nn + n0 + nn];
    }
    __syncthreads();
    #pragma unroll 8
    for (int cc = 0; cc < 32; ++cc) {
      float av[8], bv[4];
      #pragma unroll
      for (int i = 0; i < 8; ++i) av[i] = wS[tq * 8 + i][cc];
      #pragma unroll
      for (int j = 0; j < 4; ++j) bv[j] = xS[cc][tn * 4 + j];
      #pragma unroll
      for (int i = 0; i < 8; ++i)
        #pragma unroll
        for (int j = 0; j < 4; ++j)
          acc[i][j] += av[i] * bv[j];
    }
    __syncthreads();
  }
  #pragma unroll
  for (int i = 0; i < 8; ++i) {
    const int q = tq * 8 + i;
    const float inv = bns[q] * rsqrtf(bnv[q] + EPS);
    const float mu = bnm[q], bia = bnb[q];
    float4 v;
    float* vp = &v.x;
    #pragma unroll
    for (int j = 0; j < 4; ++j) {
      float t = (acc[i][j] - mu) * inv + bia;
      vp[j] = t >= 0.f ? t : SLOPE * t;
    }
    *(float4*)&qout[((size_t)b * Qq + q) * Nn + n0 + tn * 4] = v;
  }
}

__global__ __launch_bounds__(256) void k_energy(
    const float* __restrict__ x, const float* __restrict__ qf,
    float* __restrict__ part)
{
  const int q0 = blockIdx.x * 64;
  const int c0 = blockIdx.y * 64;
  const int b  = blockIdx.z / SPLIT;
  const int s  = blockIdx.z % SPLIT;
  const int tid = threadIdx.x;
  const int tc = tid & 15, tq = tid >> 4;
  __shared__ float qS[32][69];
  __shared__ float xS[32][69];
  float acc[4][4] = {};
  const float* xb = x  + ((size_t)b * Cc + c0) * Nn + s * NS;
  const float* qb = qf + ((size_t)b * Qq + q0) * Nn + s * NS;
  for (int nb = 0; nb < NS; nb += 32) {
    for (int k = tid; k < 64 * 32; k += 256) {
      int r = k >> 5, nn = k & 31;
      qS[nn][r] = qb[(size_t)r * Nn + nb + nn];
      xS[nn][r] = xb[(size_t)r * Nn + nb + nn];
    }
    __syncthreads();
    #pragma unroll 8
    for (int nn = 0; nn < 32; ++nn) {
      float av[4], bv[4];
      #pragma unroll
      for (int i = 0; i < 4; ++i) av[i] = qS[nn][tq * 4 + i];
      #pragma unroll
      for (int j = 0; j < 4; ++j) bv[j] = xS[nn][tc * 4 + j];
      #pragma unroll
      for (int i = 0; i < 4; ++i)
        #pragma unroll
        for (int j = 0; j < 4; ++j)
          acc[i][j] += av[i] * bv[j];
    }
    __syncthreads();
  }
  float* pb = part + (size_t)(b * SPLIT + s) * Qq * Cc;
  #pragma unroll
  for (int i = 0; i < 4; ++i) {
    float4 v = make_float4(acc[i][0], acc[i][1], acc[i][2], acc[i][3]);
    *(float4*)&pb[(size_t)(q0 + tq * 4 + i) * Cc + c0 + tc * 4] = v;
  }
}

__global__ __launch_bounds__(64) void k_softmax(
    const float* __restrict__ part, float* __restrict__ att)
{
  const int row = blockIdx.x;
  const int b = row >> 7, q = row & 127;
  const int lane = threadIdx.x;
  float e[8];
  #pragma unroll
  for (int j = 0; j < 8; ++j) {
    const int c = lane + 64 * j;
    float v = 0.f;
    #pragma unroll
    for (int s = 0; s < SPLIT; ++s)
      v += part[((size_t)(b * SPLIT + s) * Qq + q) * Cc + c];
    e[j] = v;
  }
  float mn = e[0];
  #pragma unroll
  for (int j = 1; j < 8; ++j) mn = fminf(mn, e[j]);
  #pragma unroll
  for (int m = 1; m < 64; m <<= 1) mn = fminf(mn, __shfl_xor(mn, m));
  float wv[8], z = 0.f;
  #pragma unroll
  for (int j = 0; j < 8; ++j) { wv[j] = expf(mn - e[j]); z += wv[j]; }
  #pragma unroll
  for (int m = 1; m < 64; m <<= 1) z += __shfl_xor(z, m);
  const float rz = 1.f / z;
  #pragma unroll
  for (int j = 0; j < 8; ++j)
    att[(size_t)row * Cc + lane + 64 * j] = wv[j] * rz;
}

__global__ __launch_bounds__(256) void k_out(
    const float* __restrict__ x, const float* __restrict__ att,
    const float* __restrict__ gamma, float* __restrict__ out)
{
  const int n0 = blockIdx.x * 64;
  const int b  = blockIdx.y;
  const int tid = threadIdx.x;
  const int tn = tid & 15, tq = tid >> 4;
  __shared__ float aS[128][33];
  __shared__ float xS[32][64];
  float acc[8][4] = {};
  const float* xb = x + (size_t)b * Cc * Nn;
  const float* ab = att + (size_t)b * Qq * Cc;
  for (int c0 = 0; c0 < Cc; c0 += 32) {
    for (int k = tid; k < 128 * 32; k += 256) {
      int r = k >> 5, cc = k & 31;
      aS[r][cc] = ab[r * Cc + c0 + cc];
    }
    for (int k = tid; k < 32 * 64; k += 256) {
      int cc = k >> 6, nn = k & 63;
      xS[cc][nn] = xb[(size_t)(c0 + cc) * Nn + n0 + nn];
    }
    __syncthreads();
    #pragma unroll 8
    for (int cc = 0; cc < 32; ++cc) {
      float av[8], bv[4];
      #pragma unroll
      for (int i = 0; i < 8; ++i) av[i] = aS[tq * 8 + i][cc];
      #pragma unroll
      for (int j = 0; j < 4; ++j) bv[j] = xS[cc][tn * 4 + j];
      #pragma unroll
      for (int i = 0; i < 8; ++i)
        #pragma unroll
        for (int j = 0; j < 4; ++j)
          acc[i][j] += av[i] * bv[j];
    }
    __syncthreads();
  }
  const float g = gamma[0];
  #pragma unroll
  for (int i = 0; i < 8; ++i) {
    const int q = tq * 8 + i;
    const size_t idx = ((size_t)b * Qq + q) * Nn + n0 + tn * 4;
    float4 qv = *(const float4*)&out[idx];
    float4 v;
    v.x = g * acc[i][0] + qv.x;
    v.y = g * acc[i][1] + qv.y;
    v.z = g * acc[i][2] + qv.z;
    v.w = g * acc[i][3] + qv.w;
    *(float4*)&out[idx] = v;
  }
}
} // namespace old

extern "C" void kernel_launch(void* const* d_in, const int* in_sizes, int n_in,
                              void* d_out, int out_size, void* d_ws, size_t ws_size,
                              hipStream_t stream) {
  (void)in_sizes; (void)n_in; (void)out_size;
  const float* x   = (const float*)d_in[0];
  const float* Wq  = (const float*)d_in[1];
  const float* bns = (const float*)d_in[2];
  const float* bnb = (const float*)d_in[3];
  const float* bnm = (const float*)d_in[4];
  const float* bnv = (const float*)d_in[5];
  const float* gam = (const float*)d_in[6];
  float* out = (float*)d_out;

  if (ws_size >= WS_NEED) {
    unsigned short* xbf  = (unsigned short*)((char*)d_ws + XBF_OFF);
    unsigned short* qbf  = (unsigned short*)((char*)d_ws + QBF_OFF);
    float*          part = (float*)((char*)d_ws + PART_OFF);
    unsigned short* attb = (unsigned short*)((char*)d_ws + ATT_OFF);
    unsigned short* wqbf = (unsigned short*)((char*)d_ws + WQBF_OFF);

    k0_wqbf<<<dim3(Qq * Cc / 1024), 256, 0, stream>>>(Wq, wqbf);
    k1_qproj<<<dim3(Nn / 128, Bb), 256, 0, stream>>>(x, wqbf, bns, bnb, bnm, bnv, gam, xbf, qbf, out);
    k2_energy<<<dim3(Bb * SPLITK, Cc / 128), 256, 0, stream>>>(xbf, qbf, gam, part);
    k3_softmax<<<dim3(Bb * Qq / 4), 256, 0, stream>>>(part, gam, attb);
    k4_out<<<dim3(Nn / 128, Bb), 256, 0, stream>>>(xbf, attb, gam, out);
  } else {
    float* part = (float*)d_ws;
    float* att  = part + (size_t)Bb * old::SPLIT * Qq * Cc;
    old::k_qproj<<<dim3(Nn / 64, Bb), 256, 0, stream>>>(x, Wq, bns, bnb, bnm, bnv, out);
    old::k_energy<<<dim3(Qq / 64, Cc / 64, Bb * old::SPLIT), 256, 0, stream>>>(x, out, part);
    old::k_softmax<<<dim3(Bb * Qq), 64, 0, stream>>>(part, att);
    old::k_out<<<dim3(Nn / 64, Bb), 256, 0, stream>>>(x, att, gam, out);
  }
}